// Round 6
// baseline (431.951 us; speedup 1.0000x reference)
//
#include <hip/hip_runtime.h>

typedef _Float16 v8h __attribute__((ext_vector_type(8)));
typedef float    v4f __attribute__((ext_vector_type(4)));

#define MFMA16(A,B,C) __builtin_amdgcn_mfma_f32_16x16x32_f16((A),(B),(C),0,0,0)

#define RPB 16
#define TT  256
#define HH  64
#define KST 136   // f16 stride per A row: k 0-63 = ha, 64-127 = hb, 8 pad
#define SG  32.0f // sigmoid-gate index scale (table step 1/32)
#define TG  64.0f // tanh-gate index scale (tanh(z)=2*sigma(2z)-1)

// All nonlinearities via LDS sigmoid LUT + lerp (ZERO transcendentals in the
// T-loop). Table: sigma(z), z in [-16,16], step 1/32, entries=(value,delta).
// Gate pre-activations exit MFMA already in index space: weights prescaled by
// 32 (sigmoid) / 64 (tanh), bias += 512. Scales are pow2 -> f16 rounding of
// weights is unchanged vs R5; lerp err <= 1.2e-5. Structure otherwise = R5.
__global__ __launch_bounds__(256, 1)
void lstm2_kernel(const float* __restrict__ x,     // [4096][256]
                  const float* __restrict__ Wih0,  // [256][1]
                  const float* __restrict__ Whh0,  // [256][64]
                  const float* __restrict__ bih0,
                  const float* __restrict__ bhh0,
                  const float* __restrict__ Wih1,  // [256][64]
                  const float* __restrict__ Whh1,  // [256][64]
                  const float* __restrict__ bih1,
                  const float* __restrict__ bhh1,
                  const float* __restrict__ Wlin,  // [64][64]
                  const float* __restrict__ blin,
                  float* __restrict__ out)         // [4096][64]
{
    __shared__ float xl[TT][RPB];                      // 16 KB, x transposed
    __shared__ __align__(16) _Float16 hs[2][RPB][KST]; // 8.5 KB double-buffered A-tile
    __shared__ float hbF[RPB][HH];                     // 4 KB
    __shared__ float2 lut[1026];                       // 8.2 KB sigmoid (val, delta)

    const int tid  = threadIdx.x;
    const int w    = tid >> 6;
    const int l15  = tid & 15;
    const int q    = (tid & 63) >> 4;
    const int row0 = (int)blockIdx.x * RPB;
    const int jj   = w * 16 + l15;

    for (int idx = tid; idx < RPB * TT; idx += 256) {
        int m = idx >> 8, t = idx & (TT - 1);
        xl[t][m] = x[(row0 + m) * TT + t];
    }
    for (int idx = tid; idx < 2 * RPB * KST; idx += 256)
        ((_Float16*)hs)[idx] = (_Float16)0.f;
    for (int i = tid; i < 1026; i += 256) {
        float z0 = (i - 512) * 0.03125f;
        float s0 = 1.0f / (1.0f + __expf(-z0));
        float s1 = 1.0f / (1.0f + __expf(-(z0 + 0.03125f)));
        lut[i] = make_float2(s0, s1 - s0);
    }

    // sigma via LUT+lerp; f is a pre-scaled table index (z*32+512)
    auto lutv = [&](float f) -> float {
        f = fminf(fmaxf(f, 0.0f), 1023.0f);
        float fl = floorf(f);
        float2 e = lut[(int)fl];
        return fmaf(f - fl, e.y, e.x);
    };

    // ---- register-stationary weights, prescaled into index space ----
    float wi0s[4], b0s[4];
    v4f   b1v[4];                       // splatted layer-1 bias (MFMA C operand)
    v8h wh0[4][2], wi1[4][2], wh1[4][2];
    #pragma unroll
    for (int tau = 0; tau < 4; tau++) {
        float sc = (tau == 2) ? TG : SG;
        int n = tau * 64 + jj;
        wi0s[tau] = Wih0[n] * sc;
        b0s[tau]  = (bih0[n] + bhh0[n]) * sc + 512.0f;
        float b1  = (bih1[n] + bhh1[n]) * sc + 512.0f;
        b1v[tau]  = (v4f){b1, b1, b1, b1};
        #pragma unroll
        for (int kk = 0; kk < 2; kk++) {
            int k0 = kk * 32 + q * 8;   // B-frag: B[k0..k0+7][n=lane&15]
            v8h a, b, c;
            #pragma unroll
            for (int j = 0; j < 8; j++) {
                a[j] = (_Float16)(Whh0[n * HH + k0 + j] * sc);
                b[j] = (_Float16)(Wih1[n * HH + k0 + j] * sc);
                c[j] = (_Float16)(Whh1[n * HH + k0 + j] * sc);
            }
            wh0[tau][kk] = a; wi1[tau][kk] = b; wh1[tau][kk] = c;
        }
    }

    float ca[4] = {0.f, 0.f, 0.f, 0.f};
    float cb[4] = {0.f, 0.f, 0.f, 0.f};
    __syncthreads();

    // ---- prologue t=0: ha(0) from x(0) only ----
    #pragma unroll
    for (int r = 0; r < 4; r++) {
        int m = q * 4 + r;
        float xv = xl[0][m];
        float iv = lutv(fmaf(xv, wi0s[0], b0s[0]));
        float gv = fmaf(2.f, lutv(fmaf(xv, wi0s[2], b0s[2])), -1.f);
        float ov = lutv(fmaf(xv, wi0s[3], b0s[3]));
        ca[r] = iv * gv;
        float tc = fmaf(2.f, lutv(fmaf(ca[r], TG, 512.f)), -1.f);
        hs[0][m][jj] = (_Float16)(ov * tc);   // ha; hb region stays 0
    }
    __syncthreads();

    // step k: reads buf[p] {ha(k-1), hb(k-2)}, writes buf[pw] {ha(k), hb(k-1)}
    auto step = [&](int k, int p, int pw, bool last) {
        v8h a0 = *(const v8h*)&hs[p][l15][q * 8];          // ha k 0-31
        v8h a1 = *(const v8h*)&hs[p][l15][32 + q * 8];     // ha k 32-63
        v8h b0 = *(const v8h*)&hs[p][l15][64 + q * 8];     // hb k 0-31
        v8h b1 = *(const v8h*)&hs[p][l15][96 + q * 8];     // hb k 32-63
        int kx = (k < TT) ? k : (TT - 1);                  // k=256: junk x, unused
        v4f xv = *(const v4f*)&xl[kx][q * 4];

        v4f acc0[4], acc1[4];
        #pragma unroll
        for (int tau = 0; tau < 4; tau++) {
            #pragma unroll
            for (int r = 0; r < 4; r++) acc0[tau][r] = fmaf(xv[r], wi0s[tau], b0s[tau]);
            acc1[tau] = MFMA16(a0, wi1[tau][0], b1v[tau]);  // bias as C operand
        }
        #pragma unroll
        for (int tau = 0; tau < 4; tau++) {
            acc0[tau] = MFMA16(a0, wh0[tau][0], acc0[tau]);
            acc0[tau] = MFMA16(a1, wh0[tau][1], acc0[tau]);
            acc1[tau] = MFMA16(a1, wi1[tau][1], acc1[tau]);
            acc1[tau] = MFMA16(b0, wh1[tau][0], acc1[tau]);
            acc1[tau] = MFMA16(b1, wh1[tau][1], acc1[tau]);
        }

        #pragma unroll
        for (int r = 0; r < 4; r++) {
            int m = q * 4 + r;
            {   // layer 0 -> ha(k)
                float iv = lutv(acc0[0][r]);
                float fv = lutv(acc0[1][r]);
                float gv = fmaf(2.f, lutv(acc0[2][r]), -1.f);
                float ov = lutv(acc0[3][r]);
                ca[r] = fmaf(fv, ca[r], iv * gv);
                float tc = fmaf(2.f, lutv(fmaf(ca[r], TG, 512.f)), -1.f);
                hs[pw][m][jj] = (_Float16)(ov * tc);
            }
            {   // layer 1 -> hb(k-1)
                float iv = lutv(acc1[0][r]);
                float fv = lutv(acc1[1][r]);
                float gv = fmaf(2.f, lutv(acc1[2][r]), -1.f);
                float ov = lutv(acc1[3][r]);
                cb[r] = fmaf(fv, cb[r], iv * gv);
                float tc = fmaf(2.f, lutv(fmaf(cb[r], TG, 512.f)), -1.f);
                float hv = ov * tc;
                hs[pw][m][64 + jj] = (_Float16)hv;
                if (last) hbF[m][jj] = hv;
            }
        }
        __syncthreads();
    };

    // k = 1..256 (k=256 = layer-1-only epilogue; its ha output junk-but-finite)
    for (int k = 1; k <= TT; k += 2) {
        step(k,     0, 1, false);
        step(k + 1, 1, 0, (k + 1) == TT);
    }

    // ---- out[m][n] = hbF[m][:] . Wlin[n][:] + blin[n] ----
    int m  = tid >> 4;
    int n0 = (tid & 15) * 4;
    float accO[4] = {blin[n0], blin[n0 + 1], blin[n0 + 2], blin[n0 + 3]};
    #pragma unroll 8
    for (int j = 0; j < HH; j++) {
        float h = hbF[m][j];
        #pragma unroll
        for (int d = 0; d < 4; d++)
            accO[d] = fmaf(h, Wlin[(n0 + d) * HH + j], accO[d]);
    }
    v4f ov = {accO[0], accO[1], accO[2], accO[3]};
    *(v4f*)&out[(row0 + m) * HH + n0] = ov;
}

extern "C" void kernel_launch(void* const* d_in, const int* in_sizes, int n_in,
                              void* d_out, int out_size, void* d_ws, size_t ws_size,
                              hipStream_t stream) {
    const float* x    = (const float*)d_in[0];
    const float* Wih0 = (const float*)d_in[1];
    const float* Whh0 = (const float*)d_in[2];
    const float* bih0 = (const float*)d_in[3];
    const float* bhh0 = (const float*)d_in[4];
    const float* Wih1 = (const float*)d_in[5];
    const float* Whh1 = (const float*)d_in[6];
    const float* bih1 = (const float*)d_in[7];
    const float* bhh1 = (const float*)d_in[8];
    const float* Wlin = (const float*)d_in[9];
    const float* blin = (const float*)d_in[10];
    // 4096 rows / 16 per block = 256 blocks = 1 per CU
    lstm2_kernel<<<256, 256, 0, stream>>>(x, Wih0, Whh0, bih0, bhh0,
                                          Wih1, Whh1, bih1, bhh1,
                                          Wlin, blin, (float*)d_out);
}

// Round 7
// 369.921 us; speedup vs baseline: 1.1677x; 1.1677x over previous
//
#include <hip/hip_runtime.h>

typedef _Float16 v8h __attribute__((ext_vector_type(8)));
typedef float    v4f __attribute__((ext_vector_type(4)));

#define MFMA16(A,B,C) __builtin_amdgcn_mfma_f32_16x16x32_f16((A),(B),(C),0,0,0)

#define RPB 8
#define TT  256
#define HH  64
#define KST 136   // f16 stride per A row: k 0-63 = ha, 64-127 = hb, 8 pad
#define SG  32.0f // sigmoid index scale (table step 1/32)
#define TG  64.0f // tanh index scale (tanh(z)=2*sigma(2z)-1)

// R6 LUT pointwise + 2 independent blocks/CU (RPB=8) for latency hiding.
// A-tile rows 0-7 = [ha||hb] K-concat of the 8 rows; rows 8-15 = DUPLICATE.
// acc0 (chunks a0,a1) -> layer0 gates; acc1 (a0,a1 via Wih1 + b0,b1 via Whh1,
// bias as C operand) -> layer1 gates. Lanes q<2 consume acc0 C-rows 0-7
// (layer0); lanes q>=2 consume acc1 C-rows 8-15 (= dup rows, layer1). Every
// lane: 4 pointwise instances, no idle lanes. One barrier/step.
__global__ __launch_bounds__(256, 2)
void lstm2_kernel(const float* __restrict__ x,     // [4096][256]
                  const float* __restrict__ Wih0,  // [256][1]
                  const float* __restrict__ Whh0,  // [256][64]
                  const float* __restrict__ bih0,
                  const float* __restrict__ bhh0,
                  const float* __restrict__ Wih1,  // [256][64]
                  const float* __restrict__ Whh1,  // [256][64]
                  const float* __restrict__ bih1,
                  const float* __restrict__ bhh1,
                  const float* __restrict__ Wlin,  // [64][64]
                  const float* __restrict__ blin,
                  float* __restrict__ out)         // [4096][64]
{
    __shared__ float xl[TT][RPB];                      // 8 KB
    __shared__ __align__(16) _Float16 hs[2][16][KST];  // 8.5 KB (rows 8-15 = dup)
    __shared__ float hbF[RPB][HH];                     // 2 KB
    __shared__ float2 lut[1026];                       // 8.2 KB sigmoid (val, delta)

    const int tid  = threadIdx.x;
    const int w    = tid >> 6;
    const int l15  = tid & 15;
    const int q    = (tid & 63) >> 4;
    const int row0 = (int)blockIdx.x * RPB;
    const int jj   = w * 16 + l15;
    const bool isA = (q < 2);          // q<2: layer-0 lanes; q>=2: layer-1 lanes
    const int  mr  = (q & 1) * 4;      // my pointwise row base (0 or 4)

    for (int idx = tid; idx < RPB * TT; idx += 256) {
        int m = idx & 7, t = idx >> 3;
        xl[t][m] = x[(row0 + m) * TT + t];
    }
    for (int idx = tid; idx < 2 * 16 * KST; idx += 256)
        ((_Float16*)hs)[idx] = (_Float16)0.f;
    for (int i = tid; i < 1026; i += 256) {
        float z0 = (i - 512) * 0.03125f;
        float s0 = 1.0f / (1.0f + __expf(-z0));
        float s1 = 1.0f / (1.0f + __expf(-(z0 + 0.03125f)));
        lut[i] = make_float2(s0, s1 - s0);
    }

    // sigma via LUT+lerp; f is a pre-scaled table index (z*32+512)
    auto lutv = [&](float f) -> float {
        f = fminf(fmaxf(f, 0.0f), 1023.0f);
        float fl = floorf(f);
        float2 e = lut[(int)fl];
        return fmaf(f - fl, e.y, e.x);
    };

    // ---- register-stationary weights, prescaled into index space ----
    float wi0s[4], b0s[4];
    v4f   b1v[4];
    v8h wh0[4][2], wi1[4][2], wh1[4][2];
    #pragma unroll
    for (int tau = 0; tau < 4; tau++) {
        float sc = (tau == 2) ? TG : SG;
        int n = tau * 64 + jj;
        wi0s[tau] = Wih0[n] * sc;
        b0s[tau]  = (bih0[n] + bhh0[n]) * sc + 512.0f;
        float b1  = (bih1[n] + bhh1[n]) * sc + 512.0f;
        b1v[tau]  = (v4f){b1, b1, b1, b1};
        #pragma unroll
        for (int kk = 0; kk < 2; kk++) {
            int k0 = kk * 32 + q * 8;   // B-frag: B[k0..k0+7][n=lane&15]
            v8h a, b, c;
            #pragma unroll
            for (int j = 0; j < 8; j++) {
                a[j] = (_Float16)(Whh0[n * HH + k0 + j] * sc);
                b[j] = (_Float16)(Wih1[n * HH + k0 + j] * sc);
                c[j] = (_Float16)(Whh1[n * HH + k0 + j] * sc);
            }
            wh0[tau][kk] = a; wi1[tau][kk] = b; wh1[tau][kk] = c;
        }
    }

    float cs[4] = {0.f, 0.f, 0.f, 0.f};  // c-state of MY layer, rows mr..mr+3
    __syncthreads();

    // ---- prologue t=0: ha(0) from x(0) only (written by q<2 lanes) ----
    if (isA) {
        #pragma unroll
        for (int r = 0; r < 4; r++) {
            int m = mr + r;
            float xv = xl[0][m];
            float iv = lutv(fmaf(xv, wi0s[0], b0s[0]));
            float gv = fmaf(2.f, lutv(fmaf(xv, wi0s[2], b0s[2])), -1.f);
            float ov = lutv(fmaf(xv, wi0s[3], b0s[3]));
            cs[r] = iv * gv;
            float tc = fmaf(2.f, lutv(fmaf(cs[r], TG, 512.f)), -1.f);
            _Float16 hh = (_Float16)(ov * tc);
            hs[0][m][jj]     = hh;
            hs[0][m + 8][jj] = hh;      // dup row
        }
    }
    __syncthreads();

    // step k: reads buf[p] {ha(k-1), hb(k-2)}, writes buf[pw] {ha(k), hb(k-1)}
    auto step = [&](int k, int p, int pw, bool last) {
        v8h a0 = *(const v8h*)&hs[p][l15][q * 8];          // ha k 0-31
        v8h a1 = *(const v8h*)&hs[p][l15][32 + q * 8];     // ha k 32-63
        v8h b0 = *(const v8h*)&hs[p][l15][64 + q * 8];     // hb k 0-31
        v8h b1 = *(const v8h*)&hs[p][l15][96 + q * 8];     // hb k 32-63
        int kx = (k < TT) ? k : (TT - 1);                  // k=256: junk x, unused
        v4f xv = *(const v4f*)&xl[kx][mr];

        v4f acc0[4], acc1[4];
        #pragma unroll
        for (int tau = 0; tau < 4; tau++) {
            #pragma unroll
            for (int r = 0; r < 4; r++) acc0[tau][r] = fmaf(xv[r], wi0s[tau], b0s[tau]);
            acc1[tau] = MFMA16(a0, wi1[tau][0], b1v[tau]);  // bias as C operand
        }
        #pragma unroll
        for (int tau = 0; tau < 4; tau++) {
            acc0[tau] = MFMA16(a0, wh0[tau][0], acc0[tau]);
            acc0[tau] = MFMA16(a1, wh0[tau][1], acc0[tau]);
            acc1[tau] = MFMA16(a1, wi1[tau][1], acc1[tau]);
            acc1[tau] = MFMA16(b0, wh1[tau][0], acc1[tau]);
            acc1[tau] = MFMA16(b1, wh1[tau][1], acc1[tau]);
        }

        // my gates: q<2 -> layer0 (acc0, C rows 0-7); q>=2 -> layer1 (acc1, dup rows)
        v4f g0 = isA ? acc0[0] : acc1[0];
        v4f g1 = isA ? acc0[1] : acc1[1];
        v4f g2 = isA ? acc0[2] : acc1[2];
        v4f g3 = isA ? acc0[3] : acc1[3];

        _Float16* wp = &hs[pw][mr][isA ? jj : (64 + jj)];

        #pragma unroll
        for (int r = 0; r < 4; r++) {
            float iv = lutv(g0[r]);
            float fv = lutv(g1[r]);
            float gv = fmaf(2.f, lutv(g2[r]), -1.f);
            float ov = lutv(g3[r]);
            cs[r] = fmaf(fv, cs[r], iv * gv);
            float tc = fmaf(2.f, lutv(fmaf(cs[r], TG, 512.f)), -1.f);
            float hv = ov * tc;
            _Float16 hh = (_Float16)hv;
            wp[r * KST]           = hh;   // primary row
            wp[(r + 8) * KST]     = hh;   // dup row
            if (last && !isA) hbF[mr + r][jj] = hv;
        }
        __syncthreads();
    };

    // k = 1..256 (k=256 = layer-1-only epilogue; its ha output junk-but-finite)
    for (int k = 1; k <= TT; k += 2) {
        step(k,     0, 1, false);
        step(k + 1, 1, 0, (k + 1) == TT);
    }

    // ---- out[m][n] = hbF[m][:] . Wlin[n][:] + blin[n] ----
    int m  = tid >> 5;            // 0..7
    int n0 = (tid & 31) * 2;
    float a0o = blin[n0], a1o = blin[n0 + 1];
    #pragma unroll 8
    for (int j = 0; j < HH; j++) {
        float h = hbF[m][j];
        a0o = fmaf(h, Wlin[(n0 + 0) * HH + j], a0o);
        a1o = fmaf(h, Wlin[(n0 + 1) * HH + j], a1o);
    }
    out[(row0 + m) * HH + n0]     = a0o;
    out[(row0 + m) * HH + n0 + 1] = a1o;
}

extern "C" void kernel_launch(void* const* d_in, const int* in_sizes, int n_in,
                              void* d_out, int out_size, void* d_ws, size_t ws_size,
                              hipStream_t stream) {
    const float* x    = (const float*)d_in[0];
    const float* Wih0 = (const float*)d_in[1];
    const float* Whh0 = (const float*)d_in[2];
    const float* bih0 = (const float*)d_in[3];
    const float* bhh0 = (const float*)d_in[4];
    const float* Wih1 = (const float*)d_in[5];
    const float* Whh1 = (const float*)d_in[6];
    const float* bih1 = (const float*)d_in[7];
    const float* bhh1 = (const float*)d_in[8];
    const float* Wlin = (const float*)d_in[9];
    const float* blin = (const float*)d_in[10];
    // 4096 rows / 8 per block = 512 blocks = 2 independent blocks/CU
    lstm2_kernel<<<512, 256, 0, stream>>>(x, Wih0, Whh0, bih0, bhh0,
                                          Wih1, Whh1, bih1, bhh1,
                                          Wlin, blin, (float*)d_out);
}

// Round 8
// 350.287 us; speedup vs baseline: 1.2331x; 1.0561x over previous
//
#include <hip/hip_runtime.h>

typedef _Float16 v8h __attribute__((ext_vector_type(8)));
typedef float    v4f __attribute__((ext_vector_type(4)));

#define MFMA16(A,B,C) __builtin_amdgcn_mfma_f32_16x16x32_f16((A),(B),(C),0,0,0)

#define RPB 8
#define TT  256
#define HH  64
#define KST 136     // f16 stride per A row: k 0-63 = ha, 64-127 = hb, 8 pad
#define SG  256.0f  // sigmoid index scale (table step 1/256)
#define TG  512.0f  // tanh index scale (tanh(z)=2*sigma(2z)-1)
#define IOFF 4096.5f // index center + 0.5 nearest-neighbor rounding offset

// R7 structure (RPB=8, 2 blocks/CU, dup-row 16x16 tile, 1 barrier/step) with
// nearest-neighbor LUT activations: 8192-entry fp32 sigma table, z in
// [-16,16] step 1/256. NN rounding offset (+0.5) folded into prescaled
// biases -> per nonlinearity: med3 clamp + cvt + lshl_add + ds_read_b32.
// NN err: sigma <= 4.9e-4, tanh <= 9.8e-4 (~ f16 h-quantization level).
__global__ __launch_bounds__(256, 2)
void lstm2_kernel(const float* __restrict__ x,     // [4096][256]
                  const float* __restrict__ Wih0,  // [256][1]
                  const float* __restrict__ Whh0,  // [256][64]
                  const float* __restrict__ bih0,
                  const float* __restrict__ bhh0,
                  const float* __restrict__ Wih1,  // [256][64]
                  const float* __restrict__ Whh1,  // [256][64]
                  const float* __restrict__ bih1,
                  const float* __restrict__ bhh1,
                  const float* __restrict__ Wlin,  // [64][64]
                  const float* __restrict__ blin,
                  float* __restrict__ out)         // [4096][64]
{
    __shared__ float xl[TT][RPB];                      // 8 KB
    __shared__ __align__(16) _Float16 hs[2][16][KST];  // 8.5 KB (rows 8-15 = dup)
    __shared__ float hbF[RPB][HH];                     // 2 KB
    __shared__ float lut[8192];                        // 32 KB sigma table

    const int tid  = threadIdx.x;
    const int w    = tid >> 6;
    const int l15  = tid & 15;
    const int q    = (tid & 63) >> 4;
    const int row0 = (int)blockIdx.x * RPB;
    const int jj   = w * 16 + l15;
    const bool isA = (q < 2);          // q<2: layer-0 lanes; q>=2: layer-1 lanes
    const int  mr  = (q & 1) * 4;      // my pointwise row base (0 or 4)

    for (int idx = tid; idx < RPB * TT; idx += 256) {
        int m = idx & 7, t = idx >> 3;
        xl[t][m] = x[(row0 + m) * TT + t];
    }
    for (int idx = tid; idx < 2 * 16 * KST; idx += 256)
        ((_Float16*)hs)[idx] = (_Float16)0.f;
    for (int i = tid; i < 8192; i += 256)
        lut[i] = 1.0f / (1.0f + __expf(-(i - 4096) * (1.0f / 256.0f)));

    // sigma via nearest-neighbor LUT; f is a pre-scaled index (z*256+4096.5)
    auto lutv = [&](float f) -> float {
        f = __builtin_amdgcn_fmed3f(f, 0.0f, 8191.0f);
        return lut[(int)f];
    };

    // ---- register-stationary weights, prescaled into index space ----
    float wi0s[4], b0s[4];
    v4f   b1v[4];
    v8h wh0[4][2], wi1[4][2], wh1[4][2];
    #pragma unroll
    for (int tau = 0; tau < 4; tau++) {
        float sc = (tau == 2) ? TG : SG;
        int n = tau * 64 + jj;
        wi0s[tau] = Wih0[n] * sc;
        b0s[tau]  = (bih0[n] + bhh0[n]) * sc + IOFF;
        float b1  = (bih1[n] + bhh1[n]) * sc + IOFF;
        b1v[tau]  = (v4f){b1, b1, b1, b1};
        #pragma unroll
        for (int kk = 0; kk < 2; kk++) {
            int k0 = kk * 32 + q * 8;   // B-frag: B[k0..k0+7][n=lane&15]
            v8h a, b, c;
            #pragma unroll
            for (int j = 0; j < 8; j++) {
                a[j] = (_Float16)(Whh0[n * HH + k0 + j] * sc);
                b[j] = (_Float16)(Wih1[n * HH + k0 + j] * sc);
                c[j] = (_Float16)(Whh1[n * HH + k0 + j] * sc);
            }
            wh0[tau][kk] = a; wi1[tau][kk] = b; wh1[tau][kk] = c;
        }
    }

    float cs[4] = {0.f, 0.f, 0.f, 0.f};  // c-state of MY layer, rows mr..mr+3
    __syncthreads();

    // ---- prologue t=0: ha(0) from x(0) only (written by q<2 lanes) ----
    if (isA) {
        #pragma unroll
        for (int r = 0; r < 4; r++) {
            int m = mr + r;
            float xv = xl[0][m];
            float iv = lutv(fmaf(xv, wi0s[0], b0s[0]));
            float gv = fmaf(2.f, lutv(fmaf(xv, wi0s[2], b0s[2])), -1.f);
            float ov = lutv(fmaf(xv, wi0s[3], b0s[3]));
            cs[r] = iv * gv;
            float tc = fmaf(2.f, lutv(fmaf(cs[r], TG, IOFF)), -1.f);
            _Float16 hh = (_Float16)(ov * tc);
            hs[0][m][jj]     = hh;
            hs[0][m + 8][jj] = hh;      // dup row
        }
    }
    __syncthreads();

    // step k: reads buf[p] {ha(k-1), hb(k-2)}, writes buf[pw] {ha(k), hb(k-1)}
    auto step = [&](int k, int p, int pw, bool last) {
        v8h a0 = *(const v8h*)&hs[p][l15][q * 8];          // ha k 0-31
        v8h a1 = *(const v8h*)&hs[p][l15][32 + q * 8];     // ha k 32-63
        v8h b0 = *(const v8h*)&hs[p][l15][64 + q * 8];     // hb k 0-31
        v8h b1 = *(const v8h*)&hs[p][l15][96 + q * 8];     // hb k 32-63
        int kx = (k < TT) ? k : (TT - 1);                  // k=256: junk x, unused
        v4f xv = *(const v4f*)&xl[kx][mr];

        v4f acc0[4], acc1[4];
        #pragma unroll
        for (int tau = 0; tau < 4; tau++) {
            #pragma unroll
            for (int r = 0; r < 4; r++) acc0[tau][r] = fmaf(xv[r], wi0s[tau], b0s[tau]);
            acc1[tau] = MFMA16(a0, wi1[tau][0], b1v[tau]);  // bias as C operand
        }
        #pragma unroll
        for (int tau = 0; tau < 4; tau++) {
            acc0[tau] = MFMA16(a0, wh0[tau][0], acc0[tau]);
            acc0[tau] = MFMA16(a1, wh0[tau][1], acc0[tau]);
            acc1[tau] = MFMA16(a1, wi1[tau][1], acc1[tau]);
            acc1[tau] = MFMA16(b0, wh1[tau][0], acc1[tau]);
            acc1[tau] = MFMA16(b1, wh1[tau][1], acc1[tau]);
        }

        // my gates: q<2 -> layer0 (acc0, C rows 0-7); q>=2 -> layer1 (acc1, dup rows)
        v4f g0 = isA ? acc0[0] : acc1[0];
        v4f g1 = isA ? acc0[1] : acc1[1];
        v4f g2 = isA ? acc0[2] : acc1[2];
        v4f g3 = isA ? acc0[3] : acc1[3];

        _Float16* wp = &hs[pw][mr][isA ? jj : (64 + jj)];

        #pragma unroll
        for (int r = 0; r < 4; r++) {
            float iv = lutv(g0[r]);
            float fv = lutv(g1[r]);
            float gv = fmaf(2.f, lutv(g2[r]), -1.f);
            float ov = lutv(g3[r]);
            cs[r] = fmaf(fv, cs[r], iv * gv);
            float tc = fmaf(2.f, lutv(fmaf(cs[r], TG, IOFF)), -1.f);
            float hv = ov * tc;
            _Float16 hh = (_Float16)hv;
            wp[r * KST]       = hh;   // primary row
            wp[(r + 8) * KST] = hh;   // dup row
            if (last && !isA) hbF[mr + r][jj] = hv;
        }
        __syncthreads();
    };

    // k = 1..256 (k=256 = layer-1-only epilogue; its ha output junk-but-finite)
    for (int k = 1; k <= TT; k += 2) {
        step(k,     0, 1, false);
        step(k + 1, 1, 0, (k + 1) == TT);
    }

    // ---- out[m][n] = hbF[m][:] . Wlin[n][:] + blin[n] ----
    int m  = tid >> 5;            // 0..7
    int n0 = (tid & 31) * 2;
    float a0o = blin[n0], a1o = blin[n0 + 1];
    #pragma unroll 8
    for (int j = 0; j < HH; j++) {
        float h = hbF[m][j];
        a0o = fmaf(h, Wlin[(n0 + 0) * HH + j], a0o);
        a1o = fmaf(h, Wlin[(n0 + 1) * HH + j], a1o);
    }
    out[(row0 + m) * HH + n0]     = a0o;
    out[(row0 + m) * HH + n0 + 1] = a1o;
}

extern "C" void kernel_launch(void* const* d_in, const int* in_sizes, int n_in,
                              void* d_out, int out_size, void* d_ws, size_t ws_size,
                              hipStream_t stream) {
    const float* x    = (const float*)d_in[0];
    const float* Wih0 = (const float*)d_in[1];
    const float* Whh0 = (const float*)d_in[2];
    const float* bih0 = (const float*)d_in[3];
    const float* bhh0 = (const float*)d_in[4];
    const float* Wih1 = (const float*)d_in[5];
    const float* Whh1 = (const float*)d_in[6];
    const float* bih1 = (const float*)d_in[7];
    const float* bhh1 = (const float*)d_in[8];
    const float* Wlin = (const float*)d_in[9];
    const float* blin = (const float*)d_in[10];
    // 4096 rows / 8 per block = 512 blocks = 2 independent blocks/CU
    lstm2_kernel<<<512, 256, 0, stream>>>(x, Wih0, Whh0, bih0, bhh0,
                                          Wih1, Whh1, bih1, bhh1,
                                          Wlin, blin, (float*)d_out);
}

// Round 9
// 342.042 us; speedup vs baseline: 1.2629x; 1.0241x over previous
//
#include <hip/hip_runtime.h>

typedef _Float16 v8h __attribute__((ext_vector_type(8)));
typedef float    v4f __attribute__((ext_vector_type(4)));

#define MFMA16(A,B,C) __builtin_amdgcn_mfma_f32_16x16x32_f16((A),(B),(C),0,0,0)

#define RPB 8
#define TT  256
#define HH  64
#define KST 136      // f16 stride per A row: k 0-63 = ha, 64-127 = hb, 8 pad
#define SG  256.0f   // sigmoid index scale (table step 1/256)
#define TG  512.0f   // g-gate tanh index scale (tanh(z)=2*sigma(2z)-1)
#define IOFF 4096.5f // index center + 0.5 NN rounding offset
#define TSC2 -2.88539008f // -2*log2(e): tanh(c)=2*rcp(1+exp2(c*TSC2))-1

// R8 minus dup-writes (A-frag reads use row l15&7 -> C rows 8-15 duplicate
// rows 0-7 with NO LDS duplication), c-tanh via exp2+rcp (kills the 2nd
// serial gather round, -20% gather traffic), staged gate gathers (one
// latency round). 2 blocks/CU, 1 barrier/step, NN sigma LUT for the 4 gates.
__global__ __launch_bounds__(256, 2)
void lstm2_kernel(const float* __restrict__ x,     // [4096][256]
                  const float* __restrict__ Wih0,  // [256][1]
                  const float* __restrict__ Whh0,  // [256][64]
                  const float* __restrict__ bih0,
                  const float* __restrict__ bhh0,
                  const float* __restrict__ Wih1,  // [256][64]
                  const float* __restrict__ Whh1,  // [256][64]
                  const float* __restrict__ bih1,
                  const float* __restrict__ bhh1,
                  const float* __restrict__ Wlin,  // [64][64]
                  const float* __restrict__ blin,
                  float* __restrict__ out)         // [4096][64]
{
    __shared__ float xl[TT][RPB];                      // 8 KB
    __shared__ __align__(16) _Float16 hs[2][RPB][KST]; // 4.25 KB (no dup rows)
    __shared__ float hbF[RPB][HH];                     // 2 KB
    __shared__ float lut[8192];                        // 32 KB sigma table

    const int tid  = threadIdx.x;
    const int w    = tid >> 6;
    const int l15  = tid & 15;
    const int l7   = tid & 7;          // A-frag row (dup-read: rows 8-15 -> 0-7)
    const int q    = (tid & 63) >> 4;
    const int row0 = (int)blockIdx.x * RPB;
    const int jj   = w * 16 + l15;
    const bool isA = (q < 2);          // q<2: layer-0 lanes; q>=2: layer-1 lanes
    const int  mr  = (q & 1) * 4;      // my pointwise row base (0 or 4)

    for (int idx = tid; idx < RPB * TT; idx += 256) {
        int m = idx & 7, t = idx >> 3;
        xl[t][m] = x[(row0 + m) * TT + t];
    }
    for (int idx = tid; idx < 2 * RPB * KST; idx += 256)
        ((_Float16*)hs)[idx] = (_Float16)0.f;
    for (int i = tid; i < 8192; i += 256)
        lut[i] = 1.0f / (1.0f + __expf(-(i - 4096) * (1.0f / 256.0f)));

    // sigma via nearest-neighbor LUT; f is a pre-scaled index (z*256+4096.5)
    auto lutv = [&](float f) -> float {
        f = __builtin_amdgcn_fmed3f(f, 0.0f, 8191.0f);
        return lut[(int)f];
    };
    // tanh via hardware exp2+rcp (near-exact, no gather)
    auto tanhf_fast = [&](float c) -> float {
        return fmaf(2.f, __builtin_amdgcn_rcpf(1.f + __builtin_exp2f(c * TSC2)), -1.f);
    };

    // ---- register-stationary weights, prescaled into index space ----
    float wi0s[4], b0s[4];
    v4f   b1v[4];
    v8h wh0[4][2], wi1[4][2], wh1[4][2];
    #pragma unroll
    for (int tau = 0; tau < 4; tau++) {
        float sc = (tau == 2) ? TG : SG;
        int n = tau * 64 + jj;
        wi0s[tau] = Wih0[n] * sc;
        b0s[tau]  = (bih0[n] + bhh0[n]) * sc + IOFF;
        float b1  = (bih1[n] + bhh1[n]) * sc + IOFF;
        b1v[tau]  = (v4f){b1, b1, b1, b1};
        #pragma unroll
        for (int kk = 0; kk < 2; kk++) {
            int k0 = kk * 32 + q * 8;   // B-frag: B[k0..k0+7][n=lane&15]
            v8h a, b, c;
            #pragma unroll
            for (int j = 0; j < 8; j++) {
                a[j] = (_Float16)(Whh0[n * HH + k0 + j] * sc);
                b[j] = (_Float16)(Wih1[n * HH + k0 + j] * sc);
                c[j] = (_Float16)(Whh1[n * HH + k0 + j] * sc);
            }
            wh0[tau][kk] = a; wi1[tau][kk] = b; wh1[tau][kk] = c;
        }
    }

    float cs[4] = {0.f, 0.f, 0.f, 0.f};  // c-state of MY layer, rows mr..mr+3
    __syncthreads();

    // ---- prologue t=0: ha(0) from x(0) only (written by q<2 lanes) ----
    if (isA) {
        #pragma unroll
        for (int r = 0; r < 4; r++) {
            int m = mr + r;
            float xv = xl[0][m];
            float iv = lutv(fmaf(xv, wi0s[0], b0s[0]));
            float gv = fmaf(2.f, lutv(fmaf(xv, wi0s[2], b0s[2])), -1.f);
            float ov = lutv(fmaf(xv, wi0s[3], b0s[3]));
            cs[r] = iv * gv;
            hs[0][m][jj] = (_Float16)(ov * tanhf_fast(cs[r]));
        }
    }
    __syncthreads();

    // step k: reads buf[p] {ha(k-1), hb(k-2)}, writes buf[pw] {ha(k), hb(k-1)}
    auto step = [&](int k, int p, int pw, bool last) {
        v8h a0 = *(const v8h*)&hs[p][l7][q * 8];          // ha k 0-31
        v8h a1 = *(const v8h*)&hs[p][l7][32 + q * 8];     // ha k 32-63
        v8h b0 = *(const v8h*)&hs[p][l7][64 + q * 8];     // hb k 0-31
        v8h b1 = *(const v8h*)&hs[p][l7][96 + q * 8];     // hb k 32-63
        int kx = (k < TT) ? k : (TT - 1);                 // k=256: junk x, unused
        v4f xv = *(const v4f*)&xl[kx][mr];

        v4f acc0[4], acc1[4];
        #pragma unroll
        for (int tau = 0; tau < 4; tau++) {
            #pragma unroll
            for (int r = 0; r < 4; r++) acc0[tau][r] = fmaf(xv[r], wi0s[tau], b0s[tau]);
            acc1[tau] = MFMA16(a0, wi1[tau][0], b1v[tau]);  // bias as C operand
        }
        #pragma unroll
        for (int tau = 0; tau < 4; tau++) {
            acc0[tau] = MFMA16(a0, wh0[tau][0], acc0[tau]);
            acc0[tau] = MFMA16(a1, wh0[tau][1], acc0[tau]);
            acc1[tau] = MFMA16(a1, wi1[tau][1], acc1[tau]);
            acc1[tau] = MFMA16(b0, wh1[tau][0], acc1[tau]);
            acc1[tau] = MFMA16(b1, wh1[tau][1], acc1[tau]);
        }

        // my gates: q<2 -> layer0 (C rows 0-7); q>=2 -> layer1 (C rows 8-15)
        v4f g0 = isA ? acc0[0] : acc1[0];
        v4f g1 = isA ? acc0[1] : acc1[1];
        v4f g2 = isA ? acc0[2] : acc1[2];
        v4f g3 = isA ? acc0[3] : acc1[3];

        // stage 1: all 16 sigma gathers issued together (one latency round)
        float sv0[4], sv1[4], sv2[4], sv3[4];
        #pragma unroll
        for (int r = 0; r < 4; r++) {
            sv0[r] = lutv(g0[r]);
            sv1[r] = lutv(g1[r]);
            sv2[r] = lutv(g2[r]);
            sv3[r] = lutv(g3[r]);
        }

        _Float16* wp = &hs[pw][mr][isA ? jj : (64 + jj)];

        // stage 2: c update, trans tanh, h write (single LDS write per value)
        #pragma unroll
        for (int r = 0; r < 4; r++) {
            float iv = sv0[r];
            float fv = sv1[r];
            float gv = fmaf(2.f, sv2[r], -1.f);
            float ov = sv3[r];
            cs[r] = fmaf(fv, cs[r], iv * gv);
            float hv = ov * tanhf_fast(cs[r]);
            wp[r * KST] = (_Float16)hv;
            if (last && !isA) hbF[mr + r][jj] = hv;
        }
        __syncthreads();
    };

    // k = 1..256 (k=256 = layer-1-only epilogue; its ha output junk-but-finite)
    for (int k = 1; k <= TT; k += 2) {
        step(k,     0, 1, false);
        step(k + 1, 1, 0, (k + 1) == TT);
    }

    // ---- out[m][n] = hbF[m][:] . Wlin[n][:] + blin[n] ----
    int m  = tid >> 5;            // 0..7
    int n0 = (tid & 31) * 2;
    float a0o = blin[n0], a1o = blin[n0 + 1];
    #pragma unroll 8
    for (int j = 0; j < HH; j++) {
        float h = hbF[m][j];
        a0o = fmaf(h, Wlin[(n0 + 0) * HH + j], a0o);
        a1o = fmaf(h, Wlin[(n0 + 1) * HH + j], a1o);
    }
    out[(row0 + m) * HH + n0]     = a0o;
    out[(row0 + m) * HH + n0 + 1] = a1o;
}

extern "C" void kernel_launch(void* const* d_in, const int* in_sizes, int n_in,
                              void* d_out, int out_size, void* d_ws, size_t ws_size,
                              hipStream_t stream) {
    const float* x    = (const float*)d_in[0];
    const float* Wih0 = (const float*)d_in[1];
    const float* Whh0 = (const float*)d_in[2];
    const float* bih0 = (const float*)d_in[3];
    const float* bhh0 = (const float*)d_in[4];
    const float* Wih1 = (const float*)d_in[5];
    const float* Whh1 = (const float*)d_in[6];
    const float* bih1 = (const float*)d_in[7];
    const float* bhh1 = (const float*)d_in[8];
    const float* Wlin = (const float*)d_in[9];
    const float* blin = (const float*)d_in[10];
    // 4096 rows / 8 per block = 512 blocks = 2 independent blocks/CU
    lstm2_kernel<<<512, 256, 0, stream>>>(x, Wih0, Whh0, bih0, bhh0,
                                          Wih1, Whh1, bih1, bhh1,
                                          Wlin, blin, (float*)d_out);
}